// Round 9
// baseline (142.535 us; speedup 1.0000x reference)
//
#include <hip/hip_runtime.h>
#include <hip/hip_cooperative_groups.h>

namespace cg = cooperative_groups;

// Tensorized (tensor-train) embedding. vocab 32000 = 8*10*20*20, out 768,
// ranks (1,16,16,16,1), B = 32768 tokens, fp32 out.
//
// Per token: out[a][mc] = sum_r2 G01[c01][a][r2] * G23[c23][r2][mc]
//   (c01 = idx/400, c23 = idx%400) -- a 16x16 @ 16x48 matmul, done as
// 3x mfma_f32_16x16x32_f16 (K zero-padded to 32) on pre-swizzled f16
// fragment tables. Per token/lane: 4 coalesced 16B loads + 3 MFMAs +
// 3 plain float4 stores (full-line-merged in L2). Zero LDS in main phase.
//
// R9: ONE cooperative kernel: blocks 0..479 build the fragment tables,
// grid.sync(), then all 1024 blocks run the R7 main phase (TPW=8, plain
// stores -- R8's nt-stores/TPW=4 both reverted: partial-line NT evictions
// and halved prologue amortization cost ~7us).
//
// Fragment maps (gfx950, m89-verified D; A/B share the k-map so the
// k-permutation cancels):
//   A[m][k]: lane l holds m = l&15, k = (l>>4)*8+j (j=0..7; k>=16 -> 0)
//   B[k][n]: lane l holds n = l&15, same k map
//   D[m][n]: lane l reg r holds m = (l>>4)*4+r, n = l&15

#define NTOK 32768
#define TPW  8
#define NBLK 1024                             // 4 blocks/CU, co-resident
#define G2F_BYTES (400 * 3 * 64 * 16)         // 1228800
#define G1F_BYTES (80 * 64 * 16)              // 81920
#define TBL_BYTES (G2F_BYTES + G1F_BYTES)     // 1310720

typedef _Float16 f16x8 __attribute__((ext_vector_type(8)));
typedef float f32x4 __attribute__((ext_vector_type(4)));

__device__ inline unsigned pack2(float x, float y) {
    _Float16 hx = (_Float16)x, hy = (_Float16)y;
    unsigned short ux = __builtin_bit_cast(unsigned short, hx);
    unsigned short uy = __builtin_bit_cast(unsigned short, hy);
    return (unsigned)ux | ((unsigned)uy << 16);
}

__device__ inline void build_phase(int b, int t,
                                   const float* __restrict__ core0,
                                   const float* __restrict__ core1,
                                   const float* __restrict__ core2,
                                   const float* __restrict__ core3,
                                   unsigned* __restrict__ g2f,
                                   unsigned* __restrict__ g1f,
                                   float* lds) {
    if (b < 400) {                          // G23 combo c23 = d2*20+d3
        int d2 = b / 20, d3 = b % 20;
#pragma unroll
        for (int i = 0; i < 3; ++i) {
            int f = t + i * 256;            // f = r2*48 + mc
            int r2 = f / 48, mc = f - r2 * 48;
            int m2 = mc >> 3, m3 = mc & 7;
            float acc = 0.f;
#pragma unroll
            for (int r3 = 0; r3 < 16; ++r3)
                acc += core2[((r2 * 20 + d2) * 6 + m2) * 16 + r3] *   // [16,20,6,16]
                       core3[(r3 * 20 + d3) * 8 + m3];                // [16,20,8,1]
            lds[f] = acc;
        }
        __syncthreads();
        int l = t >> 2, jp = t & 3;
        int k0 = ((l >> 4) << 3) + jp * 2;  // even; k0<16 <=> k0+1<16
        int mcl = l & 15;
        bool valid = k0 < 16;
#pragma unroll
        for (int p = 0; p < 3; ++p) {
            int mc = p * 16 + mcl;
            float v0 = valid ? lds[k0 * 48 + mc] : 0.f;
            float v1 = valid ? lds[(k0 + 1) * 48 + mc] : 0.f;
            g2f[(b * 3 + p) * 256 + t] = pack2(v0, v1);
        }
    } else {                                // G01 combo c01 = d0*10+d1
        int combo = b - 400;                // 0..79
        int d0 = combo / 10, d1 = combo % 10;
        int a = t >> 4, r2 = t & 15;
        int a0 = a >> 2, m1 = a & 3;
        float acc = 0.f;
#pragma unroll
        for (int r1 = 0; r1 < 16; ++r1)
            acc += core0[(d0 * 4 + a0) * 16 + r1] *                   // [1,8,4,16]
                   core1[((r1 * 10 + d1) * 4 + m1) * 16 + r2];        // [16,10,4,16]
        lds[t] = acc;                       // lds[a*16 + r2]
        __syncthreads();
        int l = t >> 2, jp = t & 3;
        int k0 = ((l >> 4) << 3) + jp * 2;
        int al = l & 15;
        bool valid = k0 < 16;
        float v0 = valid ? lds[al * 16 + k0] : 0.f;
        float v1 = valid ? lds[al * 16 + k0 + 1] : 0.f;
        g1f[combo * 256 + t] = pack2(v0, v1);
    }
}

__device__ inline void main_phase(int blk, int tid,
                                  const int* __restrict__ x,
                                  const f16x8* __restrict__ g2f,
                                  const f16x8* __restrict__ g1f,
                                  float* __restrict__ out) {
    const int wave = tid >> 6, lane = tid & 63;
    const int tok0 = (blk * 4 + wave) * TPW;

    int4 xa = ((const int4*)(x + tok0))[0];
    int4 xb = ((const int4*)(x + tok0))[1];
    int idxs[TPW] = {xa.x, xa.y, xa.z, xa.w, xb.x, xb.y, xb.z, xb.w};

    f16x8 A0, A1, A2, B;
    {
        int id = idxs[0];
        const f16x8* ap = g2f + (size_t)(id % 400) * 192 + lane;
        A0 = ap[0]; A1 = ap[64]; A2 = ap[128];
        B = g1f[(id / 400) * 64 + lane];
    }
    const f32x4 z = {0.f, 0.f, 0.f, 0.f};
    float* obase = out + (size_t)tok0 * 768 + (lane & 15) * 48 + ((lane >> 4) << 2);

#pragma unroll
    for (int t = 0; t < TPW; ++t) {
        // prefetch next token's fragments (hides L2 latency under MFMA+stores)
        int tn = (t + 1 < TPW) ? t + 1 : t;
        int id = idxs[tn];
        const f16x8* ap = g2f + (size_t)(id % 400) * 192 + lane;
        f16x8 nA0 = ap[0], nA1 = ap[64], nA2 = ap[128];
        f16x8 nB = g1f[(id / 400) * 64 + lane];

        f32x4 d0 = __builtin_amdgcn_mfma_f32_16x16x32_f16(A0, B, z, 0, 0, 0);
        f32x4 d1 = __builtin_amdgcn_mfma_f32_16x16x32_f16(A1, B, z, 0, 0, 0);
        f32x4 d2 = __builtin_amdgcn_mfma_f32_16x16x32_f16(A2, B, z, 0, 0, 0);

        float* o = obase + t * 768;
        *(f32x4*)(o)      = d0;             // p=0: mc + 0
        *(f32x4*)(o + 16) = d1;             // p=1: mc + 16
        *(f32x4*)(o + 32) = d2;             // p=2: mc + 32

        A0 = nA0; A1 = nA1; A2 = nA2; B = nB;
    }
}

// ---- fused cooperative kernel ----
__global__ __launch_bounds__(256, 4) void te_fused(const int* __restrict__ x,
                                                   const float* __restrict__ core0,
                                                   const float* __restrict__ core1,
                                                   const float* __restrict__ core2,
                                                   const float* __restrict__ core3,
                                                   unsigned* __restrict__ g2f,
                                                   unsigned* __restrict__ g1f,
                                                   float* __restrict__ out) {
    __shared__ float lds[768];
    int b = blockIdx.x, t = threadIdx.x;
    if (b < 480)
        build_phase(b, t, core0, core1, core2, core3, g2f, g1f, lds);
    cg::this_grid().sync();
    main_phase(b, t, x, (const f16x8*)g2f, (const f16x8*)g1f, out);
}

// ---- two-kernel fallback (if cooperative launch refused) ----
__global__ __launch_bounds__(256) void build_frag_tables(const float* __restrict__ core0,
                                                         const float* __restrict__ core1,
                                                         const float* __restrict__ core2,
                                                         const float* __restrict__ core3,
                                                         unsigned* __restrict__ g2f,
                                                         unsigned* __restrict__ g1f) {
    __shared__ float lds[768];
    build_phase(blockIdx.x, threadIdx.x, core0, core1, core2, core3, g2f, g1f, lds);
}

__global__ __launch_bounds__(256) void te_mfma(const int* __restrict__ x,
                                               const f16x8* __restrict__ g2f,
                                               const f16x8* __restrict__ g1f,
                                               float* __restrict__ out) {
    main_phase(blockIdx.x, threadIdx.x, x, g2f, g1f, out);
}

// ---- fallback (tiny ws): direct evaluation ----
__global__ void te_direct(const int* __restrict__ x,
                          const float* __restrict__ core0,
                          const float* __restrict__ core1,
                          const float* __restrict__ core2,
                          const float* __restrict__ core3,
                          float* __restrict__ out) {
    int tok = blockIdx.x;
    int lane = threadIdx.x;
    int idx = x[tok];
    int d0 = idx / 4000;
    int rem = idx - d0 * 4000;
    int d1 = rem / 400;
    rem -= d1 * 400;
    int d2 = rem / 20;
    int d3 = rem - d2 * 20;
    float* o = out + (size_t)tok * 768;
    for (int p = 0; p < 3; ++p) {
        int base = (p * 64 + lane) * 4;
        int a = base / 48;
        int mc = base - a * 48;
        int a0 = a >> 2, m1 = a & 3;
        float s[16];
#pragma unroll
        for (int r2 = 0; r2 < 16; ++r2) {
            float acc = 0.f;
            for (int r1 = 0; r1 < 16; ++r1)
                acc += core0[(d0 * 4 + a0) * 16 + r1] *
                       core1[((r1 * 10 + d1) * 4 + m1) * 16 + r2];
            s[r2] = acc;
        }
        float4 accv = {0.f, 0.f, 0.f, 0.f};
        float* accp = (float*)&accv;
        for (int j = 0; j < 4; ++j) {
            int mcj = mc + j;
            int m2 = mcj >> 3, m3 = mcj & 7;
            float tt = 0.f;
            for (int r2 = 0; r2 < 16; ++r2) {
                float g = 0.f;
                for (int r3 = 0; r3 < 16; ++r3)
                    g += core2[((r2 * 20 + d2) * 6 + m2) * 16 + r3] *
                         core3[(r3 * 20 + d3) * 8 + m3];
                tt += s[r2] * g;
            }
            accp[j] = tt;
        }
        *(float4*)(o + base) = accv;
    }
}

extern "C" void kernel_launch(void* const* d_in, const int* in_sizes, int n_in,
                              void* d_out, int out_size, void* d_ws, size_t ws_size,
                              hipStream_t stream) {
    const int*   x     = (const int*)d_in[0];
    const float* core0 = (const float*)d_in[1];
    const float* core1 = (const float*)d_in[2];
    const float* core2 = (const float*)d_in[3];
    const float* core3 = (const float*)d_in[4];
    float* out = (float*)d_out;

    if (ws_size >= (size_t)TBL_BYTES) {
        unsigned* g2f = (unsigned*)d_ws;
        unsigned* g1f = (unsigned*)((char*)d_ws + G2F_BYTES);

        void* args[] = {(void*)&x, (void*)&core0, (void*)&core1, (void*)&core2,
                        (void*)&core3, (void*)&g2f, (void*)&g1f, (void*)&out};
        hipError_t e = hipLaunchCooperativeKernel((const void*)te_fused,
                                                  dim3(NBLK), dim3(256),
                                                  args, 0, stream);
        if (e != hipSuccess) {
            (void)hipGetLastError();        // clear sticky error, use 2-kernel path
            build_frag_tables<<<480, 256, 0, stream>>>(core0, core1, core2, core3,
                                                       g2f, g1f);
            te_mfma<<<NBLK, 256, 0, stream>>>(x, (const f16x8*)g2f,
                                              (const f16x8*)g1f, out);
        }
    } else {
        te_direct<<<NTOK, 64, 0, stream>>>(x, core0, core1, core2, core3, out);
    }
}

// Round 10
// 27.658 us; speedup vs baseline: 5.1535x; 5.1535x over previous
//
#include <hip/hip_runtime.h>

// Tensorized (tensor-train) embedding. vocab 32000 = 8*10*20*20, out 768,
// ranks (1,16,16,16,1), B = 32768 tokens, fp32 out.
//
// Per token: out[a][mc] = sum_r2 G01[c01][a][r2] * G23[c23][r2][mc]
//   (c01 = idx/400, c23 = idx%400) -- a 16x16 @ 16x48 matmul, done as
// 3x mfma_f32_16x16x16f16 (K=16 exact) on pre-swizzled f16 fragment
// tables, computing the transposed tile (A = G2^T chunk, B = G1^T) so each
// lane's 4 accs are 4 consecutive mc of one output row.
//
// R10: revert R9's cooperative fusion (grid.sync serialized everything);
// back to two kernels. vs R7: K=32->16 MFMA (no zero padding), fragments
// repacked to 32B/lane/token in 3 loads (16B+8B+8B), prefetch depth 2.
//
// Fragment maps (gfx950): A[m][k]: lane l holds m=l&15, k=(l>>4)*4+j
// (j=0..3); B[k][n]: n=l&15, same k-map (A/B symmetric -> builder's
// k-permutation cancels). D[m][n]: lane l reg r: m=(l>>4)*4+r, n=l&15
// (shape-determined, m89-verified).

#define NTOK 32768
#define TPW  8
#define NBLK (NTOK / (4 * TPW))               // 1024
#define G2A01_BYTES (400 * 64 * 16)           // 409600
#define G2A2_BYTES  (400 * 64 * 8)            // 204800
#define G1B_BYTES   (80 * 64 * 8)             // 40960
#define TBL_BYTES   (G2A01_BYTES + G2A2_BYTES + G1B_BYTES)  // 655360

typedef _Float16 f16x4 __attribute__((ext_vector_type(4)));
typedef _Float16 f16x8 __attribute__((ext_vector_type(8)));
typedef float f32x4 __attribute__((ext_vector_type(4)));

__device__ inline unsigned pack2(float x, float y) {
    _Float16 hx = (_Float16)x, hy = (_Float16)y;
    unsigned short ux = __builtin_bit_cast(unsigned short, hx);
    unsigned short uy = __builtin_bit_cast(unsigned short, hy);
    return (unsigned)ux | ((unsigned)uy << 16);
}

// ---- kernel A: build f16 fragment tables (480 blocks) ----
__global__ __launch_bounds__(256) void build_frag_tables(const float* __restrict__ core0,
                                                         const float* __restrict__ core1,
                                                         const float* __restrict__ core2,
                                                         const float* __restrict__ core3,
                                                         unsigned* __restrict__ g2a01,
                                                         unsigned* __restrict__ g2a2,
                                                         unsigned* __restrict__ g1b) {
    __shared__ float lds[768];
    int b = blockIdx.x, t = threadIdx.x;
    int l = t & 63, part = t >> 6;          // lane 0..63, part 0..3
    if (b < 400) {                          // G23 combo c23 = d2*20+d3
        int d2 = b / 20, d3 = b % 20;
#pragma unroll
        for (int i = 0; i < 3; ++i) {
            int f = t + i * 256;            // f = r2*48 + mc
            int r2 = f / 48, mc = f - r2 * 48;
            int m2 = mc >> 3, m3 = mc & 7;
            float acc = 0.f;
#pragma unroll
            for (int r3 = 0; r3 < 16; ++r3)
                acc += core2[((r2 * 20 + d2) * 6 + m2) * 16 + r3] *   // [16,20,6,16]
                       core3[(r3 * 20 + d3) * 8 + m3];                // [16,20,8,1]
            lds[f] = acc;
        }
        __syncthreads();
        {   // A01 record: 4 u32/lane; this thread writes u32 'part'
            int pp = part >> 1;             // chunk p' = 0,1 (mc 0-15 / 16-31)
            int jp = part & 1;              // k-pair within frag
            int k = ((l >> 4) << 2) + jp * 2;
            int mc = pp * 16 + (l & 15);
            g2a01[(b * 64 + l) * 4 + part] = pack2(lds[k * 48 + mc],
                                                   lds[(k + 1) * 48 + mc]);
        }
        if (part < 2) {                     // A2 record: 2 u32/lane (mc 32-47)
            int k = ((l >> 4) << 2) + part * 2;
            int mc = 32 + (l & 15);
            g2a2[(b * 64 + l) * 2 + part] = pack2(lds[k * 48 + mc],
                                                  lds[(k + 1) * 48 + mc]);
        }
    } else {                                // G01 combo c01 = d0*10+d1
        int combo = b - 400;                // 0..79
        int d0 = combo / 10, d1 = combo % 10;
        int a = t >> 4, r2 = t & 15;
        int a0 = a >> 2, m1 = a & 3;
        float acc = 0.f;
#pragma unroll
        for (int r1 = 0; r1 < 16; ++r1)
            acc += core0[(d0 * 4 + a0) * 16 + r1] *                   // [1,8,4,16]
                   core1[((r1 * 10 + d1) * 4 + m1) * 16 + r2];        // [16,10,4,16]
        lds[t] = acc;                       // lds[a*16 + r2]
        __syncthreads();
        if (part < 2) {                     // B record: 2 u32/lane
            int k = ((l >> 4) << 2) + part * 2;   // r2
            int n = l & 15;                       // a
            g1b[(combo * 64 + l) * 2 + part] = pack2(lds[n * 16 + k],
                                                     lds[n * 16 + k + 1]);
        }
    }
}

// ---- kernel B: MFMA main, zero LDS, depth-2 prefetch ----
struct Frag { f16x8 a01; f16x4 a2; f16x4 b; };

__device__ inline Frag load_frag(int id, int lane,
                                 const f16x8* __restrict__ g2a01,
                                 const f16x4* __restrict__ g2a2,
                                 const f16x4* __restrict__ g1b) {
    Frag f;
    int c23 = id % 400, c01 = id / 400;
    f.a01 = g2a01[c23 * 64 + lane];
    f.a2  = g2a2[c23 * 64 + lane];
    f.b   = g1b[c01 * 64 + lane];
    return f;
}

__global__ __launch_bounds__(256) void te_mfma(const int* __restrict__ x,
                                               const f16x8* __restrict__ g2a01,
                                               const f16x4* __restrict__ g2a2,
                                               const f16x4* __restrict__ g1b,
                                               float* __restrict__ out) {
    const int wave = threadIdx.x >> 6, lane = threadIdx.x & 63;
    const int tok0 = (blockIdx.x * 4 + wave) * TPW;

    int4 xa = ((const int4*)(x + tok0))[0];
    int4 xb = ((const int4*)(x + tok0))[1];
    int idxs[TPW] = {xa.x, xa.y, xa.z, xa.w, xb.x, xb.y, xb.z, xb.w};

    Frag f0 = load_frag(idxs[0], lane, g2a01, g2a2, g1b);
    Frag f1 = load_frag(idxs[1], lane, g2a01, g2a2, g1b);

    const f32x4 z = {0.f, 0.f, 0.f, 0.f};
    float* obase = out + (size_t)tok0 * 768 + (lane & 15) * 48 + ((lane >> 4) << 2);

#pragma unroll
    for (int t = 0; t < TPW; ++t) {
        Frag f2 = f1;
        if (t + 2 < TPW)                    // depth-2 prefetch
            f2 = load_frag(idxs[t + 2], lane, g2a01, g2a2, g1b);

        f16x4 a0 = __builtin_shufflevector(f0.a01, f0.a01, 0, 1, 2, 3);
        f16x4 a1 = __builtin_shufflevector(f0.a01, f0.a01, 4, 5, 6, 7);
        f32x4 d0 = __builtin_amdgcn_mfma_f32_16x16x16f16(a0,    f0.b, z, 0, 0, 0);
        f32x4 d1 = __builtin_amdgcn_mfma_f32_16x16x16f16(a1,    f0.b, z, 0, 0, 0);
        f32x4 d2 = __builtin_amdgcn_mfma_f32_16x16x16f16(f0.a2, f0.b, z, 0, 0, 0);

        float* o = obase + t * 768;
        *(f32x4*)(o)      = d0;             // mc chunk 0
        *(f32x4*)(o + 16) = d1;             // mc chunk 1
        *(f32x4*)(o + 32) = d2;             // mc chunk 2

        f0 = f1; f1 = f2;
    }
}

// ---- fallback (tiny ws): direct evaluation ----
__global__ void te_direct(const int* __restrict__ x,
                          const float* __restrict__ core0,
                          const float* __restrict__ core1,
                          const float* __restrict__ core2,
                          const float* __restrict__ core3,
                          float* __restrict__ out) {
    int tok = blockIdx.x;
    int lane = threadIdx.x;
    int idx = x[tok];
    int d0 = idx / 4000;
    int rem = idx - d0 * 4000;
    int d1 = rem / 400;
    rem -= d1 * 400;
    int d2 = rem / 20;
    int d3 = rem - d2 * 20;
    float* o = out + (size_t)tok * 768;
    for (int p = 0; p < 3; ++p) {
        int base = (p * 64 + lane) * 4;
        int a = base / 48;
        int mc = base - a * 48;
        int a0 = a >> 2, m1 = a & 3;
        float s[16];
#pragma unroll
        for (int r2 = 0; r2 < 16; ++r2) {
            float acc = 0.f;
            for (int r1 = 0; r1 < 16; ++r1)
                acc += core0[(d0 * 4 + a0) * 16 + r1] *
                       core1[((r1 * 10 + d1) * 4 + m1) * 16 + r2];
            s[r2] = acc;
        }
        float4 accv = {0.f, 0.f, 0.f, 0.f};
        float* accp = (float*)&accv;
        for (int j = 0; j < 4; ++j) {
            int mcj = mc + j;
            int m2 = mcj >> 3, m3 = mcj & 7;
            float tt = 0.f;
            for (int r2 = 0; r2 < 16; ++r2) {
                float g = 0.f;
                for (int r3 = 0; r3 < 16; ++r3)
                    g += core2[((r2 * 20 + d2) * 6 + m2) * 16 + r3] *
                         core3[(r3 * 20 + d3) * 8 + m3];
                tt += s[r2] * g;
            }
            accp[j] = tt;
        }
        *(float4*)(o + base) = accv;
    }
}

extern "C" void kernel_launch(void* const* d_in, const int* in_sizes, int n_in,
                              void* d_out, int out_size, void* d_ws, size_t ws_size,
                              hipStream_t stream) {
    const int*   x     = (const int*)d_in[0];
    const float* core0 = (const float*)d_in[1];
    const float* core1 = (const float*)d_in[2];
    const float* core2 = (const float*)d_in[3];
    const float* core3 = (const float*)d_in[4];
    float* out = (float*)d_out;

    if (ws_size >= (size_t)TBL_BYTES) {
        unsigned* g2a01 = (unsigned*)d_ws;
        unsigned* g2a2  = (unsigned*)((char*)d_ws + G2A01_BYTES);
        unsigned* g1b   = (unsigned*)((char*)d_ws + G2A01_BYTES + G2A2_BYTES);
        build_frag_tables<<<480, 256, 0, stream>>>(core0, core1, core2, core3,
                                                   g2a01, g2a2, g1b);
        // 1024 blocks x 4 waves x 8 tokens = 32768 exactly
        te_mfma<<<NBLK, 256, 0, stream>>>(x, (const f16x8*)g2a01,
                                          (const f16x4*)g2a2,
                                          (const f16x4*)g1b, out);
    } else {
        te_direct<<<NTOK, 64, 0, stream>>>(x, core0, core1, core2, core3, out);
    }
}